// Round 3
// baseline (207.940 us; speedup 1.0000x reference)
//
#include <hip/hip_runtime.h>
#include <stdint.h>

// Problem constants (fixed by the reference)
#define H 56
#define W 56
#define HW (H * W)          // 3136
#define CIN 256
#define NGRP 64             // feature_group_count
#define IMG (CIN * HW)      // 802816 elements per image
#define EPS 1e-5f

#define TS 58               // tile with 1-px halo on each side
#define TSTRIDE 64          // padded row stride (bytes) in LDS

// Strict fp32 RN ops, immune to -ffp-contract (inline asm cannot be fused).
__device__ __forceinline__ float mul_rn(float a, float b) {
    float d;
    asm("v_mul_f32 %0, %1, %2" : "=v"(d) : "v"(a), "v"(b));
    return d;
}
__device__ __forceinline__ float add_rn(float a, float b) {
    float d;
    asm("v_add_f32 %0, %1, %2" : "=v"(d) : "v"(a), "v"(b));
    return d;
}
__device__ __forceinline__ float sub_rn(float a, float b) {
    float d;
    asm("v_sub_f32 %0, %1, %2" : "=v"(d) : "v"(a), "v"(b));
    return d;
}

// ---------------------------------------------------------------------------
// Kernel 1: pack ternarized weights. Per c_out: 4 u32 words:
//   [0] sign lo (bits 0..31), [1] sign hi (bits 32..35)   sign bit = (w > 0)
//   [2] nz   lo,              [3] nz   hi                 nz bit   = (w != 0)
// Bit index: bit = tap*4 + ci, tap = kh*3 + kw.
// ---------------------------------------------------------------------------
__global__ void pack_weights_kernel(const float* __restrict__ w,
                                    uint32_t* __restrict__ wb) {
    int c = blockIdx.x * blockDim.x + threadIdx.x;
    if (c >= CIN) return;
    uint32_t slo = 0, shi = 0, zlo = 0, zhi = 0;
    const float* wc = w + c * 36;       // [c][ci][kh][kw], 4*9 = 36
    for (int ci = 0; ci < 4; ++ci) {
        for (int t = 0; t < 9; ++t) {
            int b = t * 4 + ci;
            float v = wc[ci * 9 + t];
            uint32_t s = (v > 0.f) ? 1u : 0u;
            uint32_t z = (v != 0.f) ? 1u : 0u;
            if (b < 32) { slo |= s << b;       zlo |= z << b; }
            else        { shi |= s << (b-32);  zhi |= z << (b-32); }
        }
    }
    wb[c * 4]     = slo;
    wb[c * 4 + 1] = shi;
    wb[c * 4 + 2] = zlo;
    wb[c * 4 + 3] = zhi;
}

// ---------------------------------------------------------------------------
// Kernel 2: BN -> sign (ternary, sign(0)=0) -> XNOR-popcount grouped 3x3 conv
//           -> channel shuffle -> + x
// One block per (n, g). 256 threads.
// BN chain must match np fp32 bit-exactly:
//   s    = sqrt(var + eps)          (correctly rounded)
//   r    = 1 / s                    (correctly rounded)
//   inv  = gamma * r                (RN mul)
//   bias = beta - mean * inv        (RN mul, RN sub — NO fma contraction)
//   t    = x * inv + bias           (RN mul, RN add — NO fma contraction)
// The exact-zero case t == 0 (sign -> 0) only reproduces with this chain.
// ---------------------------------------------------------------------------
__global__ __launch_bounds__(256)
void binconv_kernel(const float* __restrict__ X,
                    const uint32_t* __restrict__ wb,
                    const float* __restrict__ gamma,
                    const float* __restrict__ beta,
                    const float* __restrict__ mean,
                    const float* __restrict__ var,
                    float* __restrict__ out) {
    __shared__ uint8_t tile_s[TS * TSTRIDE];   // sign nibbles (bit ci = t>0)
    __shared__ uint8_t tile_z[TS * TSTRIDE];   // nonzero nibbles (bit ci = t!=0)

    const int bx  = blockIdx.x;
    const int n   = bx >> 6;
    const int g   = bx & 63;
    const int tid = threadIdx.x;

    float inv[4], bias[4];
#pragma unroll
    for (int ci = 0; ci < 4; ++ci) {
        int c = g * 4 + ci;
        float s  = sqrtf(var[c] + EPS);   // correctly rounded (hipcc default)
        float r  = 1.0f / s;              // correctly rounded division
        float iv = mul_rn(gamma[c], r);
        inv[ci]  = iv;
        bias[ci] = sub_rn(beta[c], mul_rn(mean[c], iv));
    }

    const float* Xn = X + (size_t)n * IMG;

    // Phase A: ternarize 4 channels into nibble planes (halo: z=0 -> masked)
    for (int p = tid; p < TS * TS; p += 256) {
        int y  = p / TS;
        int xx = p - y * TS;
        int hy = y - 1, wx = xx - 1;
        uint32_t sn = 0, zn = 0;
        if ((unsigned)hy < (unsigned)H && (unsigned)wx < (unsigned)W) {
            int off = hy * W + wx;
#pragma unroll
            for (int ci = 0; ci < 4; ++ci) {
                float v = Xn[(g * 4 + ci) * HW + off];
                float t = add_rn(mul_rn(v, inv[ci]), bias[ci]);
                sn |= (t > 0.f  ? 1u : 0u) << ci;
                zn |= (t != 0.f ? 1u : 0u) << ci;
            }
        }
        tile_s[y * TSTRIDE + xx] = (uint8_t)sn;
        tile_z[y * TSTRIDE + xx] = (uint8_t)zn;
    }

    // Packed weights for the 4 output channels of this group
    uint32_t wslo[4], wshi[4], wzlo[4], wzhi[4];
#pragma unroll
    for (int j = 0; j < 4; ++j) {
        const uint32_t* p4 = &wb[(g * 4 + j) * 4];
        wslo[j] = p4[0]; wshi[j] = p4[1]; wzlo[j] = p4[2]; wzhi[j] = p4[3];
    }

    __syncthreads();

    // Phase B: per output pixel, build 36-bit sign + nz words, 4x XOR+popcnt
    for (int p = tid; p < HW; p += 256) {
        int h = p / W;
        int w = p - h * W;

        const int base = h * TSTRIDE + w;
        const uint8_t* s0 = &tile_s[base];
        const uint8_t* z0 = &tile_z[base];

        uint32_t r0s = (uint32_t)s0[0] | ((uint32_t)s0[1] << 4) | ((uint32_t)s0[2] << 8);
        uint32_t r1s = (uint32_t)s0[TSTRIDE]   | ((uint32_t)s0[TSTRIDE+1]   << 4) | ((uint32_t)s0[TSTRIDE+2]   << 8);
        uint32_t r2s = (uint32_t)s0[2*TSTRIDE] | ((uint32_t)s0[2*TSTRIDE+1] << 4) | ((uint32_t)s0[2*TSTRIDE+2] << 8);
        uint32_t r0z = (uint32_t)z0[0] | ((uint32_t)z0[1] << 4) | ((uint32_t)z0[2] << 8);
        uint32_t r1z = (uint32_t)z0[TSTRIDE]   | ((uint32_t)z0[TSTRIDE+1]   << 4) | ((uint32_t)z0[TSTRIDE+2]   << 8);
        uint32_t r2z = (uint32_t)z0[2*TSTRIDE] | ((uint32_t)z0[2*TSTRIDE+1] << 4) | ((uint32_t)z0[2*TSTRIDE+2] << 8);

        uint32_t alo = r0s | (r1s << 12) | ((r2s & 0xFFu) << 24);
        uint32_t ahi = r2s >> 8;
        uint32_t zlo = r0z | (r1z << 12) | ((r2z & 0xFFu) << 24);
        uint32_t zhi = r2z >> 8;

        float res[4];
#pragma unroll
        for (int j = 0; j < 4; ++j) {
            uint32_t ml = zlo & wzlo[j];
            uint32_t mh = zhi & wzhi[j];
            int vb = __popc(ml) + __popc(mh);
            int pc = __popc((alo ^ wslo[j]) & ml) + __popc((ahi ^ wshi[j]) & mh);
            res[j] = (float)(vb - 2 * pc);
        }

        // Shuffled destination channels: c' = j*64 + g ; shortcut = x[c']
        size_t obase = (size_t)n * IMG + (size_t)p;
#pragma unroll
        for (int j = 0; j < 4; ++j) {
            size_t idx = obase + (size_t)(j * 64 + g) * HW;
            out[idx] = add_rn(res[j], X[idx]);
        }
    }
}

// ---------------------------------------------------------------------------
extern "C" void kernel_launch(void* const* d_in, const int* in_sizes, int n_in,
                              void* d_out, int out_size, void* d_ws, size_t ws_size,
                              hipStream_t stream) {
    const float* X     = (const float*)d_in[0];
    const float* Wt    = (const float*)d_in[1];
    const float* gamma = (const float*)d_in[2];
    const float* beta  = (const float*)d_in[3];
    const float* mean  = (const float*)d_in[4];
    const float* var   = (const float*)d_in[5];
    float* out = (float*)d_out;
    uint32_t* wb = (uint32_t*)d_ws;   // 256 * 4 * 4B = 4 KB of scratch

    int N = in_sizes[0] / IMG;        // 32

    pack_weights_kernel<<<1, 256, 0, stream>>>(Wt, wb);
    binconv_kernel<<<N * NGRP, 256, 0, stream>>>(X, wb, gamma, beta, mean, var, out);
}

// Round 4
// 205.120 us; speedup vs baseline: 1.0137x; 1.0137x over previous
//
#include <hip/hip_runtime.h>
#include <stdint.h>

// Problem constants (fixed by the reference)
#define H 56
#define W 56
#define HW (H * W)          // 3136
#define CIN 256
#define IMG (CIN * HW)      // 802816 elements per image
#define EPS 1e-5f

#define ROWW 8              // u32 words per tile row: 32B = 64 nibbles
#define TROWS 58            // 56 image rows + top/bottom padding rows

// Strict fp32 RN ops, immune to -ffp-contract (inline asm cannot be fused).
// Round 3 proved the np reference's exact-zero BN outputs (sign->0) only
// reproduce with the two-rounding chain round(round(x*inv)+bias).
__device__ __forceinline__ float mul_rn(float a, float b) {
    float d; asm("v_mul_f32 %0, %1, %2" : "=v"(d) : "v"(a), "v"(b)); return d;
}
__device__ __forceinline__ float add_rn(float a, float b) {
    float d; asm("v_add_f32 %0, %1, %2" : "=v"(d) : "v"(a), "v"(b)); return d;
}
__device__ __forceinline__ float sub_rn(float a, float b) {
    float d; asm("v_sub_f32 %0, %1, %2" : "=v"(d) : "v"(a), "v"(b)); return d;
}

// ---------------------------------------------------------------------------
// Fused: BN -> ternary sign -> XNOR-popcount grouped 3x3 conv -> shuffle -> +x
// One block per (n, g), 256 threads, 4 pixels per thread-task.
//
// LDS layout per plane: 58 rows x 8 u32; row r+1 holds image row r as packed
// 4-bit nibbles (nibble w = 4 channel bits of pixel w). Rows 0/57 and nibble
// columns 56..63 stay zero => z-plane zeros subsume all geometric padding.
// ---------------------------------------------------------------------------
__global__ __launch_bounds__(256)
void binconv_kernel(const float* __restrict__ X,
                    const float* __restrict__ Wt,
                    const float* __restrict__ gamma,
                    const float* __restrict__ beta,
                    const float* __restrict__ mean,
                    const float* __restrict__ var,
                    float* __restrict__ out) {
    __shared__ uint32_t s_tile[TROWS * ROWW];   // sign nibbles
    __shared__ uint32_t z_tile[TROWS * ROWW];   // nonzero nibbles
    __shared__ uint32_t ws_l[4][3];             // weight sign rows (12-bit)
    __shared__ uint32_t wz_l[4][3];             // weight nz   rows (12-bit)

    const int bx  = blockIdx.x;
    const int n   = bx >> 6;
    const int g   = bx & 63;
    const int tid = threadIdx.x;

    // Zero both tiles (interior is overwritten after the barrier).
    for (int i = tid; i < TROWS * ROWW; i += 256) { s_tile[i] = 0u; z_tile[i] = 0u; }

    // Threads 0..3 pack this group's 4 filters into 12-bit row patterns.
    // bit = kw*4 + ci  (kw aligns with window nibble: w-1, w, w+1).
    if (tid < 4) {
        const float* wc = Wt + (size_t)(g * 4 + tid) * 36;   // [ci][kh][kw]
        for (int r = 0; r < 3; ++r) {
            uint32_t s = 0, z = 0;
            for (int ci = 0; ci < 4; ++ci)
                for (int kw = 0; kw < 3; ++kw) {
                    float v = wc[ci * 9 + r * 3 + kw];
                    int b = kw * 4 + ci;
                    s |= (v > 0.f  ? 1u : 0u) << b;
                    z |= (v != 0.f ? 1u : 0u) << b;
                }
            ws_l[tid][r] = s; wz_l[tid][r] = z;
        }
    }

    // BN constants (strict np fp32 chain — see round-3 notes).
    float inv[4], bias[4];
#pragma unroll
    for (int ci = 0; ci < 4; ++ci) {
        int c = g * 4 + ci;
        float s  = sqrtf(var[c] + EPS);   // correctly rounded
        float r  = 1.0f / s;              // correctly rounded
        float iv = mul_rn(gamma[c], r);
        inv[ci]  = iv;
        bias[ci] = sub_rn(beta[c], mul_rn(mean[c], iv));
    }

    __syncthreads();

    const float* Xn = X + (size_t)n * IMG;

    // Phase A: 56 rows x 14 col-groups of 4 px; float4 loads, b16 LDS writes.
    for (int task = tid; task < 56 * 14; task += 256) {
        int r  = task / 14;
        int cg = task - r * 14;
        int off = r * W + cg * 4;
        uint32_t s16 = 0, z16 = 0;
#pragma unroll
        for (int ci = 0; ci < 4; ++ci) {
            const float4 v = *reinterpret_cast<const float4*>(
                Xn + (size_t)(g * 4 + ci) * HW + off);
            float t0 = add_rn(mul_rn(v.x, inv[ci]), bias[ci]);
            float t1 = add_rn(mul_rn(v.y, inv[ci]), bias[ci]);
            float t2 = add_rn(mul_rn(v.z, inv[ci]), bias[ci]);
            float t3 = add_rn(mul_rn(v.w, inv[ci]), bias[ci]);
            s16 |= ((t0 > 0.f ? 1u : 0u) << ci)        | ((t1 > 0.f ? 1u : 0u) << (4 + ci))
                 | ((t2 > 0.f ? 1u : 0u) << (8 + ci))  | ((t3 > 0.f ? 1u : 0u) << (12 + ci));
            z16 |= ((t0 != 0.f ? 1u : 0u) << ci)       | ((t1 != 0.f ? 1u : 0u) << (4 + ci))
                 | ((t2 != 0.f ? 1u : 0u) << (8 + ci)) | ((t3 != 0.f ? 1u : 0u) << (12 + ci));
        }
        // tile row r+1, nibbles cg*4..cg*4+3 -> aligned u16 index cg
        reinterpret_cast<uint16_t*>(&s_tile[(r + 1) * ROWW])[cg] = (uint16_t)s16;
        reinterpret_cast<uint16_t*>(&z_tile[(r + 1) * ROWW])[cg] = (uint16_t)z16;
    }

    __syncthreads();

    // Weights to registers; uniform fast-path flag (no exactly-zero weights).
    uint32_t wsj[4][3], wzj[4][3];
    bool full = true;
#pragma unroll
    for (int j = 0; j < 4; ++j)
#pragma unroll
        for (int r = 0; r < 3; ++r) {
            wsj[j][r] = ws_l[j][r];
            wzj[j][r] = wz_l[j][r];
            full = full && (wzj[j][r] == 0xFFFu);
        }

    float* On = out + (size_t)n * IMG;

    // Phase B: per task = (output row h, 4-px group), 6 two-dword LDS reads.
    for (int task = tid; task < 56 * 14; task += 256) {
        int h  = task / 14;
        int cg = task - h * 14;
        int w0 = cg * 4;

        uint64_t vs[3], vz[3];
        int off;
        if (w0 == 0) {
            off = 0;
#pragma unroll
            for (int r = 0; r < 3; ++r) {
                int base = (h + r) * ROWW;
                vs[r] = (((uint64_t)s_tile[base] | ((uint64_t)s_tile[base + 1] << 32)) << 4);
                vz[r] = (((uint64_t)z_tile[base] | ((uint64_t)z_tile[base + 1] << 32)) << 4);
            }
        } else {
            int st = 4 * w0 - 4;
            int i0 = st >> 5;
            off = st & 31;
#pragma unroll
            for (int r = 0; r < 3; ++r) {
                int base = (h + r) * ROWW + i0;
                vs[r] = ((uint64_t)s_tile[base] | ((uint64_t)s_tile[base + 1] << 32));
                vz[r] = ((uint64_t)z_tile[base] | ((uint64_t)z_tile[base + 1] << 32));
            }
        }

        int res[4][4];
        if (full) {
#pragma unroll
            for (int k = 0; k < 4; ++k) {
                int sh = off + 4 * k;
                uint32_t s0 = (uint32_t)(vs[0] >> sh) & 0xFFFu;
                uint32_t s1 = (uint32_t)(vs[1] >> sh) & 0xFFFu;
                uint32_t s2 = (uint32_t)(vs[2] >> sh) & 0xFFFu;
                uint32_t z0 = (uint32_t)(vz[0] >> sh) & 0xFFFu;
                uint32_t z1 = (uint32_t)(vz[1] >> sh) & 0xFFFu;
                uint32_t z2 = (uint32_t)(vz[2] >> sh) & 0xFFFu;
                int vb = __popc(z0) + __popc(z1) + __popc(z2);
#pragma unroll
                for (int j = 0; j < 4; ++j) {
                    int pc = __popc((s0 ^ wsj[j][0]) & z0)
                           + __popc((s1 ^ wsj[j][1]) & z1)
                           + __popc((s2 ^ wsj[j][2]) & z2);
                    res[j][k] = vb - 2 * pc;
                }
            }
        } else {
#pragma unroll
            for (int k = 0; k < 4; ++k) {
                int sh = off + 4 * k;
                uint32_t s0 = (uint32_t)(vs[0] >> sh) & 0xFFFu;
                uint32_t s1 = (uint32_t)(vs[1] >> sh) & 0xFFFu;
                uint32_t s2 = (uint32_t)(vs[2] >> sh) & 0xFFFu;
                uint32_t z0 = (uint32_t)(vz[0] >> sh) & 0xFFFu;
                uint32_t z1 = (uint32_t)(vz[1] >> sh) & 0xFFFu;
                uint32_t z2 = (uint32_t)(vz[2] >> sh) & 0xFFFu;
#pragma unroll
                for (int j = 0; j < 4; ++j) {
                    uint32_t m0 = z0 & wzj[j][0];
                    uint32_t m1 = z1 & wzj[j][1];
                    uint32_t m2 = z2 & wzj[j][2];
                    int vb = __popc(m0) + __popc(m1) + __popc(m2);
                    int pc = __popc((s0 ^ wsj[j][0]) & m0)
                           + __popc((s1 ^ wsj[j][1]) & m1)
                           + __popc((s2 ^ wsj[j][2]) & m2);
                    res[j][k] = vb - 2 * pc;
                }
            }
        }

        // Epilogue: shuffled channel c' = j*64 + g; float4 shortcut + store.
        size_t pbase = (size_t)h * W + w0;
#pragma unroll
        for (int j = 0; j < 4; ++j) {
            size_t cofs = (size_t)(j * 64 + g) * HW + pbase;
            const float4 sc = *reinterpret_cast<const float4*>(Xn + cofs);
            float4 o;
            o.x = add_rn((float)res[j][0], sc.x);
            o.y = add_rn((float)res[j][1], sc.y);
            o.z = add_rn((float)res[j][2], sc.z);
            o.w = add_rn((float)res[j][3], sc.w);
            *reinterpret_cast<float4*>(On + cofs) = o;
        }
    }
}

// ---------------------------------------------------------------------------
extern "C" void kernel_launch(void* const* d_in, const int* in_sizes, int n_in,
                              void* d_out, int out_size, void* d_ws, size_t ws_size,
                              hipStream_t stream) {
    const float* X     = (const float*)d_in[0];
    const float* Wt    = (const float*)d_in[1];
    const float* gamma = (const float*)d_in[2];
    const float* beta  = (const float*)d_in[3];
    const float* mean  = (const float*)d_in[4];
    const float* var   = (const float*)d_in[5];
    float* out = (float*)d_out;

    int N = in_sizes[0] / IMG;        // 32

    binconv_kernel<<<N * 64, 256, 0, stream>>>(X, Wt, gamma, beta, mean, var, out);
}